// Round 4
// baseline (423.522 us; speedup 1.0000x reference)
//
#include <hip/hip_runtime.h>

// GNN, fixed shapes: B=128 graphs x N=64 nodes, D=64 features, M=8192, HL=3, OL=2.
// adjacency [8192x8192] f32 is block-diagonal (128 diagonal 64x64 symmetric 0/1
// blocks). All float tensors f32; fingerprints int32.
//
// R4: 256 blocks (2 per graph, feature-column halves) x 128 threads. gnn_k is
// LDS-BW-bound, so doubling active CUs + 4x4 tiles with b128-only GEMM operands
// halves the LDS cycles per CU per iteration. Pre-norm column halves are
// exchanged through global memory across the (already required) BN grid
// barrier. Head stays a separate 1-block kernel.
#define MT   8192
#define DD   64
#define NPG  64
#define XP   68          // xsc column stride (floats)
#define WSS  33          // wTh stride
#define HSS  36          // hs stride
#define BN_EPS 1e-5f

__device__ __forceinline__ float selu_f(float x) {
  const float scale = 1.0507009873554804934f;
  const float alpha = 1.6732632423543772848f;
  return x > 0.f ? scale * x : scale * alpha * (__expf(x) - 1.f);
}

// Device-scope sense barrier. All 256 blocks co-resident (43KB LDS, 2 waves ->
// >=4 blocks/CU capacity on 256 CUs).
__device__ __forceinline__ void gbar(int* cnt, int* gen) {
  __syncthreads();
  if (threadIdx.x == 0) {
    int g = __hip_atomic_load(gen, __ATOMIC_RELAXED, __HIP_MEMORY_SCOPE_AGENT);
    int a = __hip_atomic_fetch_add(cnt, 1, __ATOMIC_ACQ_REL, __HIP_MEMORY_SCOPE_AGENT);
    if (a == (int)gridDim.x - 1) {
      __hip_atomic_store(cnt, 0, __ATOMIC_RELAXED, __HIP_MEMORY_SCOPE_AGENT);
      __hip_atomic_store(gen, g + 1, __ATOMIC_RELEASE, __HIP_MEMORY_SCOPE_AGENT);
    } else {
      while (__hip_atomic_load(gen, __ATOMIC_ACQUIRE, __HIP_MEMORY_SCOPE_AGENT) == g)
        __builtin_amdgcn_s_sleep(1);
    }
  }
  __syncthreads();
}

__global__ __launch_bounds__(128) void gnn_k(
    const int* __restrict__ fpr,
    const float* __restrict__ emb,     // [NFP,64]
    const float* __restrict__ adj,     // [8192,8192]
    const float* __restrict__ Wf,      // [3,64,64]
    const float* __restrict__ bfv,     // [3,64]
    float* __restrict__ mol,           // out [128,64]
    float* __restrict__ xg,            // exchange [128 graphs][64 cols][64 n]
    float* __restrict__ stats,         // [3*128] zeroed (sum|sumsq per layer)
    int* __restrict__ bar)             // [2] zeroed (cnt, gen)
{
  __shared__ float xsc[XP * 64];          // x col-major: xsc[d*XP + n], full 64 cols
  __shared__ float wTh[64 * WSS];         // wTh[k*WSS + clocal] = W[cglob][k]
  __shared__ float hs[64 * HSS];          // hs[n*HSS + clocal]
  __shared__ unsigned char aU[64 * 64];   // aU[r*64 + k] = A[r][k] (symmetric)
  __shared__ float red1[512], red2[512];  // 16 trgroups x 32 local cols
  __shared__ float mus[64], rss[64];

  const int tid = threadIdx.x;
  const int bq  = blockIdx.x;
  const int b   = bq >> 1;          // graph
  const int q   = bq & 1;           // column half
  const int tr  = tid >> 3;         // 0..15
  const int tc  = tid & 7;          // 0..7
  const int n0  = tr * 4;
  const int c0  = tc * 4;           // local col base (0..28)
  const int cg0 = q * 32 + c0;      // global col base

  // ---- stage A block (bytes) ----
  for (int j = 0; j < 8; ++j) {
    int e = (tid + j * 128) * 4;
    int r = e >> 6, k = e & 63;
    float4 av = *(const float4*)(adj + (size_t)(b * NPG + r) * MT + b * NPG + k);
    uchar4 u;
    u.x = (unsigned char)av.x; u.y = (unsigned char)av.y;
    u.z = (unsigned char)av.z; u.w = (unsigned char)av.w;
    *(uchar4*)(aU + e) = u;
  }
  // ---- stage W^T half for layer 0: rows q*32..q*32+31 ----
  for (int j = 0; j < 4; ++j) {
    int e = (tid + j * 128) * 4;
    int r = e >> 6, k = e & 63;             // r = local out-feature 0..31
    float4 wv = *(const float4*)(Wf + (size_t)(q * 32 + r) * DD + k);
    wTh[(k + 0) * WSS + r] = wv.x;
    wTh[(k + 1) * WSS + r] = wv.y;
    wTh[(k + 2) * WSS + r] = wv.z;
    wTh[(k + 3) * WSS + r] = wv.w;
  }
  // ---- stage x: embedding gather, full 64 columns, col-major ----
  for (int j = 0; j < 8; ++j) {
    int e = (tid + j * 128) * 4;
    int r = e >> 6, k = e & 63;
    int f = fpr[b * NPG + r];
    float4 xv = *(const float4*)(emb + (size_t)f * DD + k);
    xsc[(k + 0) * XP + r] = xv.x;
    xsc[(k + 1) * XP + r] = xv.y;
    xsc[(k + 2) * XP + r] = xv.z;
    xsc[(k + 3) * XP + r] = xv.w;
  }
  __syncthreads();

  for (int l = 0; l < 3; ++l) {
    // ---- GEMM1: h[n][c] = selu(sum_d x[n][d] W[cg][d] + b[cg]) ----
    {
      float acc[4][4] = {};
#pragma unroll 4
      for (int d = 0; d < DD; ++d) {
        float4 xv = *(const float4*)(xsc + d * XP + n0);
        float4 wv = *(const float4*)(wTh + d * WSS + c0);
#pragma unroll
        for (int i = 0; i < 4; ++i) {
          float xk = ((const float*)&xv)[i];
          acc[i][0] += xk * wv.x;
          acc[i][1] += xk * wv.y;
          acc[i][2] += xk * wv.z;
          acc[i][3] += xk * wv.w;
        }
      }
      float b4[4];
#pragma unroll
      for (int c = 0; c < 4; ++c) b4[c] = bfv[l * DD + cg0 + c];
#pragma unroll
      for (int i = 0; i < 4; ++i) {
        float4 hv;
        hv.x = selu_f(acc[i][0] + b4[0]);
        hv.y = selu_f(acc[i][1] + b4[1]);
        hv.z = selu_f(acc[i][2] + b4[2]);
        hv.w = selu_f(acc[i][3] + b4[3]);
        *(float4*)(hs + (n0 + i) * HSS + c0) = hv;
      }
    }
    __syncthreads();

    // ---- GEMM2: y = x + A @ h (A via symmetry: aU[k*64+n] = A[n][k]) ----
    {
      float acc[4][4] = {};
#pragma unroll 4
      for (int k = 0; k < DD; ++k) {
        uchar4 a4 = *(const uchar4*)(aU + k * DD + n0);
        float4 hv = *(const float4*)(hs + k * HSS + c0);
        float af[4] = { (float)a4.x, (float)a4.y, (float)a4.z, (float)a4.w };
#pragma unroll
        for (int i = 0; i < 4; ++i) {
          acc[i][0] += af[i] * hv.x;
          acc[i][1] += af[i] * hv.y;
          acc[i][2] += af[i] * hv.z;
          acc[i][3] += af[i] * hv.w;
        }
      }
      // residual + in-place xsc update (own cells), stats partials, exchange write
#pragma unroll
      for (int c = 0; c < 4; ++c) {
        float* p = xsc + (cg0 + c) * XP + n0;
        float4 xo = *(const float4*)p;
        float y0 = acc[0][c] + xo.x;
        float y1 = acc[1][c] + xo.y;
        float y2 = acc[2][c] + xo.z;
        float y3 = acc[3][c] + xo.w;
        float4 yv = { y0, y1, y2, y3 };
        *(float4*)p = yv;
        if (l < 2)
          *(float4*)(xg + (size_t)(b * DD + cg0 + c) * NPG + n0) = yv;  // pre-norm
        red1[tr * 32 + c0 + c] = y0 + y1 + y2 + y3;
        red2[tr * 32 + c0 + c] = y0 * y0 + y1 * y1 + y2 * y2 + y3 * y3;
      }
    }
    __syncthreads();
    if (tid < 32) {
      float t1 = 0.f, t2 = 0.f;
#pragma unroll
      for (int t = 0; t < 16; ++t) { t1 += red1[t * 32 + tid]; t2 += red2[t * 32 + tid]; }
      atomicAdd(&stats[l * 128 + q * 32 + tid], t1);
      atomicAdd(&stats[l * 128 + DD + q * 32 + tid], t2);
    }

    gbar(bar, bar + 1);   // stats complete + all xg halves visible

    if (tid < DD) {
      float s1 = __hip_atomic_load(&stats[l * 128 + tid], __ATOMIC_RELAXED,
                                   __HIP_MEMORY_SCOPE_AGENT);
      float s2 = __hip_atomic_load(&stats[l * 128 + DD + tid], __ATOMIC_RELAXED,
                                   __HIP_MEMORY_SCOPE_AGENT);
      float mu  = s1 * (1.f / MT);
      float var = fmaxf(s2 * (1.f / MT) - mu * mu, 0.f);
      mus[tid] = mu;
      rss[tid] = rsqrtf(var + BN_EPS);
    }
    __syncthreads();

    if (l < 2) {
      // normalize own half in place
#pragma unroll
      for (int c = 0; c < 4; ++c) {
        float mu = mus[cg0 + c], rs = rss[cg0 + c];
        float* p = xsc + (cg0 + c) * XP + n0;
        float4 v = *(const float4*)p;
        v.x = (v.x - mu) * rs; v.y = (v.y - mu) * rs;
        v.z = (v.z - mu) * rs; v.w = (v.w - mu) * rs;
        *(float4*)p = v;
      }
      // fetch + normalize the other half
      const int qo = 1 - q;
      for (int j = 0; j < 4; ++j) {
        int e = (tid + j * 128) * 4;
        int co = e >> 6, n = e & 63;
        int d = qo * 32 + co;
        float4 v = *(const float4*)(xg + (size_t)(b * DD + d) * NPG + n);
        float mu = mus[d], rs = rss[d];
        v.x = (v.x - mu) * rs; v.y = (v.y - mu) * rs;
        v.z = (v.z - mu) * rs; v.w = (v.w - mu) * rs;
        *(float4*)(xsc + d * XP + n) = v;
      }
      // restage wTh for layer l+1
      for (int j = 0; j < 4; ++j) {
        int e = (tid + j * 128) * 4;
        int r = e >> 6, k = e & 63;
        float4 wv = *(const float4*)(Wf + (size_t)(l + 1) * 4096 +
                                     (size_t)(q * 32 + r) * DD + k);
        wTh[(k + 0) * WSS + r] = wv.x;
        wTh[(k + 1) * WSS + r] = wv.y;
        wTh[(k + 2) * WSS + r] = wv.z;
        wTh[(k + 3) * WSS + r] = wv.w;
      }
      __syncthreads();
    } else {
      // last layer: normalize own half + pool partials
#pragma unroll
      for (int c = 0; c < 4; ++c) {
        float mu = mus[cg0 + c], rs = rss[cg0 + c];
        float* p = xsc + (cg0 + c) * XP + n0;
        float4 v = *(const float4*)p;
        v.x = (v.x - mu) * rs; v.y = (v.y - mu) * rs;
        v.z = (v.z - mu) * rs; v.w = (v.w - mu) * rs;
        red1[tr * 32 + c0 + c] = v.x + v.y + v.z + v.w;
      }
      __syncthreads();
      if (tid < 32) {
        float s = 0.f;
#pragma unroll
        for (int t = 0; t < 16; ++t) s += red1[t * 32 + tid];
        mol[b * DD + q * 32 + tid] = s * (1.f / NPG);
      }
    }
  }
}

// Output MLP head in one block: 2x (selu(mol @ Wo^T + bo) -> batchnorm over 128
// rows), then mol @ Wp + bp -> f32 out[128].
__global__ __launch_bounds__(512) void final_k(
    const float* __restrict__ mol,
    const float* __restrict__ Wo,   // [2,64,64]
    const float* __restrict__ bo,   // [2,64]
    const float* __restrict__ Wp,   // [64]
    const float* __restrict__ bp,   // [1]
    float* __restrict__ out)        // [128]
{
  __shared__ float t[128 * 65];
  __shared__ float wT[64 * 64];
  __shared__ float red1[8 * 64], red2[8 * 64];
  __shared__ float mus[64], rss[64];

  const int tid  = threadIdx.x;
  const int lane = tid & 63;
  const int w    = tid >> 6;          // 0..7

  for (int j = 0; j < 16; ++j) {
    int e = tid + j * 512;
    t[(e >> 6) * 65 + (e & 63)] = mol[e];
  }

  float acc[16];
  for (int layer = 0; layer < 2; ++layer) {
    __syncthreads();
    for (int j = 0; j < 8; ++j) {
      int e = tid + j * 512;
      wT[(e & 63) * 64 + (e >> 6)] = Wo[layer * 4096 + e];
    }
    float bias = bo[layer * 64 + lane];
    __syncthreads();
#pragma unroll
    for (int j = 0; j < 16; ++j) acc[j] = bias;
    for (int k = 0; k < 64; ++k) {
      float wv = wT[k * 64 + lane];
#pragma unroll
      for (int j = 0; j < 16; ++j)
        acc[j] += t[(w + 8 * j) * 65 + k] * wv;
    }
    float s1 = 0.f, s2 = 0.f;
#pragma unroll
    for (int j = 0; j < 16; ++j) {
      acc[j] = selu_f(acc[j]);
      s1 += acc[j]; s2 += acc[j] * acc[j];
    }
    red1[w * 64 + lane] = s1;
    red2[w * 64 + lane] = s2;
    __syncthreads();
    if (tid < 64) {
      float a1 = 0.f, a2 = 0.f;
#pragma unroll
      for (int q = 0; q < 8; ++q) { a1 += red1[q * 64 + tid]; a2 += red2[q * 64 + tid]; }
      float mu  = a1 * (1.f / 128);
      float var = fmaxf(a2 * (1.f / 128) - mu * mu, 0.f);
      mus[tid] = mu;
      rss[tid] = rsqrtf(var + BN_EPS);
    }
    __syncthreads();
#pragma unroll
    for (int j = 0; j < 16; ++j)
      t[(w + 8 * j) * 65 + lane] = (acc[j] - mus[lane]) * rss[lane];
  }
  __syncthreads();
  if (tid < 128) {
    float a = bp[0];
#pragma unroll
    for (int d = 0; d < 64; ++d) a += t[tid * 65 + d] * Wp[d];
    out[tid] = a;
  }
}

extern "C" void kernel_launch(void* const* d_in, const int* in_sizes, int n_in,
                              void* d_out, int out_size, void* d_ws, size_t ws_size,
                              hipStream_t stream) {
  (void)in_sizes; (void)n_in; (void)out_size; (void)ws_size;
  const int*   fpr = (const int*)d_in[0];
  const float* adj = (const float*)d_in[1];
  const float* emb = (const float*)d_in[2];
  const float* Wf  = (const float*)d_in[3];
  const float* bfv = (const float*)d_in[4];
  const float* Wo  = (const float*)d_in[5];
  const float* bo  = (const float*)d_in[6];
  const float* Wp  = (const float*)d_in[7];
  const float* bp  = (const float*)d_in[8];

  float* ws    = (float*)d_ws;
  float* stats = ws;                 // 384 floats
  int*   bar   = (int*)(ws + 384);   // 2 ints
  float* mol   = ws + 512;           // 8192 floats
  float* xg    = ws + 512 + 8192;    // 524288 floats (exchange)

  hipMemsetAsync(ws, 0, (384 + 2) * sizeof(float), stream);

  gnn_k<<<256, 128, 0, stream>>>(fpr, emb, adj, Wf, bfv, mol, xg, stats, bar);
  final_k<<<1, 512, 0, stream>>>(mol, Wo, bo, Wp, bp, (float*)d_out);
}

// Round 5
// 392.802 us; speedup vs baseline: 1.0782x; 1.0782x over previous
//
#include <hip/hip_runtime.h>

// GNN, fixed shapes: B=128 graphs x N=64 nodes, D=64 features, M=8192, HL=3, OL=2.
// adjacency [8192x8192] f32 is block-diagonal (128 diagonal 64x64 symmetric 0/1
// blocks). All float tensors f32; fingerprints int32.
//
// R5: best-measured R3 structure (128 persistent blocks x 256 threads, one per
// graph, x resident in LDS, 3 BN grid barriers) + the output-MLP head fused in:
// a 4th grid barrier, then block 0 runs the head while other blocks retire.
// Single worker launch + 1.5KB memset. Layer GEMM thread-mapping is the R3 one
// (4x4 tiles, operand reads are 4/16-way lane-duplicated -> LDS broadcasts).
#define MT   8192
#define DD   64
#define NPG  64
#define NB   128
#define XP   68          // xsc/wT column stride (floats)
#define TP   68          // head t row stride (floats), 16B-aligned rows
#define BN_EPS 1e-5f

__device__ __forceinline__ float selu_f(float x) {
  const float scale = 1.0507009873554804934f;
  const float alpha = 1.6732632423543772848f;
  return x > 0.f ? scale * x : scale * alpha * (__expf(x) - 1.f);
}

// Device-scope sense barrier. 128 blocks, 56KB LDS, 256 thr -> all co-resident.
__device__ __forceinline__ void gbar(int* cnt, int* gen) {
  __syncthreads();
  if (threadIdx.x == 0) {
    int g = __hip_atomic_load(gen, __ATOMIC_RELAXED, __HIP_MEMORY_SCOPE_AGENT);
    int a = __hip_atomic_fetch_add(cnt, 1, __ATOMIC_ACQ_REL, __HIP_MEMORY_SCOPE_AGENT);
    if (a == (int)gridDim.x - 1) {
      __hip_atomic_store(cnt, 0, __ATOMIC_RELAXED, __HIP_MEMORY_SCOPE_AGENT);
      __hip_atomic_store(gen, g + 1, __ATOMIC_RELEASE, __HIP_MEMORY_SCOPE_AGENT);
    } else {
      while (__hip_atomic_load(gen, __ATOMIC_ACQUIRE, __HIP_MEMORY_SCOPE_AGENT) == g)
        __builtin_amdgcn_s_sleep(1);
    }
  }
  __syncthreads();
}

__global__ __launch_bounds__(256) void gnn_k(
    const int* __restrict__ fpr,
    const float* __restrict__ emb,     // [NFP,64]
    const float* __restrict__ adj,     // [8192,8192]
    const float* __restrict__ Wf,      // [3,64,64]
    const float* __restrict__ bfv,     // [3,64]
    const float* __restrict__ Wo,      // [2,64,64]
    const float* __restrict__ bo,      // [2,64]
    const float* __restrict__ Wp,      // [64]
    const float* __restrict__ bp,      // [1]
    float* __restrict__ out,           // [128]
    float* __restrict__ mol,           // scratch [128,64]
    float* __restrict__ stats,         // [3*128] zeroed (sum|sumsq per layer)
    int* __restrict__ bar)             // [2] zeroed (cnt, gen)
{
  __shared__ char pool[55808];
  float* xsc = (float*)pool;                   // [0,17408): x col-major xsc[d*XP+n]
  float* wT  = (float*)(pool + 17408);         // [17408,34816): wT[k*XP+c]=W[c][k]
  float* hs  = (float*)(pool + 34816);         // [34816,51200): hs[n*64+d]
  unsigned char* aU = (unsigned char*)(pool + 51200); // [51200,55296): A bytes
  float* mus = (float*)(pool + 55296);         // 256 B
  float* rss = (float*)(pool + 55552);         // 256 B
  float* red1 = wT;                            // overlay (wT dead at that point)
  float* red2 = wT + 1024;

  const int tid = threadIdx.x, b = blockIdx.x;
  const int tr = tid >> 4, tc = tid & 15;
  const int n0 = tr * 4, c0 = tc * 4;

  // ---- stage A block (bytes), W^T(layer0), x (embed gather, col-major) ----
  for (int j = 0; j < 4; ++j) {
    int e = (tid + j * 256) * 4;
    int r = e >> 6, k = e & 63;
    float4 av = *(const float4*)(adj + (size_t)(b * NPG + r) * MT + b * NPG + k);
    uchar4 u;
    u.x = (unsigned char)av.x; u.y = (unsigned char)av.y;
    u.z = (unsigned char)av.z; u.w = (unsigned char)av.w;
    *(uchar4*)(aU + e) = u;
    float4 wv = *(const float4*)(Wf + e);          // W[r][k..k+3]
    wT[(k + 0) * XP + r] = wv.x;
    wT[(k + 1) * XP + r] = wv.y;
    wT[(k + 2) * XP + r] = wv.z;
    wT[(k + 3) * XP + r] = wv.w;
    int f = fpr[b * NPG + r];
    float4 xv = *(const float4*)(emb + (size_t)f * DD + k);
    xsc[(k + 0) * XP + r] = xv.x;
    xsc[(k + 1) * XP + r] = xv.y;
    xsc[(k + 2) * XP + r] = xv.z;
    xsc[(k + 3) * XP + r] = xv.w;
  }
  __syncthreads();

  float poolp = 0.f;

  for (int l = 0; l < 3; ++l) {
    // ---- GEMM1: h = selu(x @ W^T + b); operand reads are lane-duplicated ----
    {
      float acc[4][4] = {};
#pragma unroll 4
      for (int d = 0; d < DD; ++d) {
        float4 xv = *(const float4*)(xsc + d * XP + n0);
        float4 wv = *(const float4*)(wT + d * XP + c0);
#pragma unroll
        for (int i = 0; i < 4; ++i) {
          float xk = ((const float*)&xv)[i];
          acc[i][0] += xk * wv.x;
          acc[i][1] += xk * wv.y;
          acc[i][2] += xk * wv.z;
          acc[i][3] += xk * wv.w;
        }
      }
      float b4[4];
#pragma unroll
      for (int c = 0; c < 4; ++c) b4[c] = bfv[l * DD + c0 + c];
#pragma unroll
      for (int i = 0; i < 4; ++i) {
        float4 hv;
        hv.x = selu_f(acc[i][0] + b4[0]);
        hv.y = selu_f(acc[i][1] + b4[1]);
        hv.z = selu_f(acc[i][2] + b4[2]);
        hv.w = selu_f(acc[i][3] + b4[3]);
        *(float4*)(hs + (n0 + i) * DD + c0) = hv;
      }
    }
    __syncthreads();   // hs ready; wT dead -> red1/red2 usable

    // ---- GEMM2: y = x + A @ h (A via symmetry: aU[k*64+n] = A[n][k]) ----
    {
      float acc[4][4] = {};
#pragma unroll 4
      for (int k = 0; k < DD; ++k) {
        uchar4 a4 = *(const uchar4*)(aU + k * DD + n0);
        float4 hv = *(const float4*)(hs + k * DD + c0);
        float af[4] = { (float)a4.x, (float)a4.y, (float)a4.z, (float)a4.w };
#pragma unroll
        for (int i = 0; i < 4; ++i) {
          acc[i][0] += af[i] * hv.x;
          acc[i][1] += af[i] * hv.y;
          acc[i][2] += af[i] * hv.z;
          acc[i][3] += af[i] * hv.w;
        }
      }
#pragma unroll
      for (int c = 0; c < 4; ++c) {
        float* p = xsc + (c0 + c) * XP + n0;
        float4 xo = *(const float4*)p;
        float y0 = acc[0][c] + xo.x;
        float y1 = acc[1][c] + xo.y;
        float y2 = acc[2][c] + xo.z;
        float y3 = acc[3][c] + xo.w;
        float4 yv = { y0, y1, y2, y3 };
        *(float4*)p = yv;
        red1[tr * DD + c0 + c] = y0 + y1 + y2 + y3;
        red2[tr * DD + c0 + c] = y0 * y0 + y1 * y1 + y2 * y2 + y3 * y3;
      }
    }
    __syncthreads();
    if (tid < DD) {
      float t1 = 0.f, t2 = 0.f;
#pragma unroll
      for (int q = 0; q < 16; ++q) { t1 += red1[q * DD + tid]; t2 += red2[q * DD + tid]; }
      atomicAdd(&stats[l * 128 + tid], t1);
      atomicAdd(&stats[l * 128 + DD + tid], t2);
    }

    gbar(bar, bar + 1);   // batch-global BN stats complete

    if (tid < DD) {
      float s1 = __hip_atomic_load(&stats[l * 128 + tid], __ATOMIC_RELAXED,
                                   __HIP_MEMORY_SCOPE_AGENT);
      float s2 = __hip_atomic_load(&stats[l * 128 + DD + tid], __ATOMIC_RELAXED,
                                   __HIP_MEMORY_SCOPE_AGENT);
      float mu  = s1 * (1.f / MT);
      float var = fmaxf(s2 * (1.f / MT) - mu * mu, 0.f);
      mus[tid] = mu;
      rss[tid] = rsqrtf(var + BN_EPS);
    }
    __syncthreads();

    // ---- normalize xsc in place; thread owns column d = tid>>2, quarter q ----
    {
      int d = tid >> 2, q = tid & 3;
      float mu = mus[d], rs = rss[d];
      float* p = xsc + d * XP + q * 16;
      float ps = 0.f;
#pragma unroll
      for (int w = 0; w < 4; ++w) {
        float4 v = *(const float4*)(p + w * 4);
        v.x = (v.x - mu) * rs; v.y = (v.y - mu) * rs;
        v.z = (v.z - mu) * rs; v.w = (v.w - mu) * rs;
        *(float4*)(p + w * 4) = v;
        ps += v.x + v.y + v.z + v.w;
      }
      poolp = ps;
    }
    if (l < 2) {
      for (int j = 0; j < 4; ++j) {
        int e = (tid + j * 256) * 4;
        int r = e >> 6, k = e & 63;
        float4 wv = *(const float4*)(Wf + (size_t)(l + 1) * 4096 + e);
        wT[(k + 0) * XP + r] = wv.x;
        wT[(k + 1) * XP + r] = wv.y;
        wT[(k + 2) * XP + r] = wv.z;
        wT[(k + 3) * XP + r] = wv.w;
      }
    } else {
      red1[tid] = poolp;   // pooling partials (wT region free on last layer)
    }
    __syncthreads();
  }

  // ---- pool: mean over the 64 nodes of this graph ----
  if (tid < DD) {
    float s = red1[tid * 4] + red1[tid * 4 + 1] + red1[tid * 4 + 2] + red1[tid * 4 + 3];
    mol[b * DD + tid] = s * (1.f / NPG);
  }

  gbar(bar, bar + 1);      // all mol rows visible
  if (b != 0) return;

  // ================= output MLP head, block 0 only =================
  // Overlays: t[128][TP] on [0,34816); wty unused; wT2 on hs region;
  // hred1/hred2 on aU region; mus/rss reused.
  float* t     = (float*)pool;                 // 128*TP floats = 34816 B
  float* wT2   = hs;                           // wT2[k*64+c] = Wo[c][k], 16384 B
  float* hred1 = (float*)(pool + 51200);       // 4*64 floats
  float* hred2 = (float*)(pool + 52224);       // 4*64 floats

  const int lane = tid & 63;
  const int w4   = tid >> 6;            // 0..3

  for (int j = 0; j < 32; ++j) {
    int e = tid + j * 256;
    t[(e >> 6) * TP + (e & 63)] = mol[e];
  }

  float acc[32];
  for (int layer = 0; layer < 2; ++layer) {
    __syncthreads();
    for (int j = 0; j < 16; ++j) {
      int e = tid + j * 256;
      wT2[(e & 63) * 64 + (e >> 6)] = Wo[layer * 4096 + e];
    }
    float bias = bo[layer * 64 + lane];
    __syncthreads();
#pragma unroll
    for (int j = 0; j < 32; ++j) acc[j] = bias;
    for (int k = 0; k < 64; k += 4) {
      float wv0 = wT2[(k + 0) * 64 + lane];
      float wv1 = wT2[(k + 1) * 64 + lane];
      float wv2 = wT2[(k + 2) * 64 + lane];
      float wv3 = wT2[(k + 3) * 64 + lane];
#pragma unroll
      for (int j = 0; j < 32; ++j) {
        float4 tv = *(const float4*)(t + (w4 + 4 * j) * TP + k);  // broadcast
        acc[j] += tv.x * wv0 + tv.y * wv1 + tv.z * wv2 + tv.w * wv3;
      }
    }
    float s1 = 0.f, s2 = 0.f;
#pragma unroll
    for (int j = 0; j < 32; ++j) {
      acc[j] = selu_f(acc[j]);
      s1 += acc[j]; s2 += acc[j] * acc[j];
    }
    hred1[w4 * 64 + lane] = s1;
    hred2[w4 * 64 + lane] = s2;
    __syncthreads();
    if (tid < 64) {
      float a1 = 0.f, a2 = 0.f;
#pragma unroll
      for (int q = 0; q < 4; ++q) { a1 += hred1[q * 64 + tid]; a2 += hred2[q * 64 + tid]; }
      float mu  = a1 * (1.f / 128);
      float var = fmaxf(a2 * (1.f / 128) - mu * mu, 0.f);
      mus[tid] = mu;
      rss[tid] = rsqrtf(var + BN_EPS);
    }
    __syncthreads();
#pragma unroll
    for (int j = 0; j < 32; ++j)
      t[(w4 + 4 * j) * TP + lane] = (acc[j] - mus[lane]) * rss[lane];
  }
  __syncthreads();
  if (tid < 128) {
    float a = bp[0];
#pragma unroll 16
    for (int d = 0; d < 64; ++d) a += t[tid * TP + d] * Wp[d];
    out[tid] = a;
  }
}

extern "C" void kernel_launch(void* const* d_in, const int* in_sizes, int n_in,
                              void* d_out, int out_size, void* d_ws, size_t ws_size,
                              hipStream_t stream) {
  (void)in_sizes; (void)n_in; (void)out_size; (void)ws_size;
  const int*   fpr = (const int*)d_in[0];
  const float* adj = (const float*)d_in[1];
  const float* emb = (const float*)d_in[2];
  const float* Wf  = (const float*)d_in[3];
  const float* bfv = (const float*)d_in[4];
  const float* Wo  = (const float*)d_in[5];
  const float* bo  = (const float*)d_in[6];
  const float* Wp  = (const float*)d_in[7];
  const float* bp  = (const float*)d_in[8];

  float* ws    = (float*)d_ws;
  float* stats = ws;                 // 384 floats
  int*   bar   = (int*)(ws + 384);   // 2 ints
  float* mol   = ws + 512;           // 8192 floats

  hipMemsetAsync(ws, 0, (384 + 2) * sizeof(float), stream);

  gnn_k<<<NB, 256, 0, stream>>>(fpr, emb, adj, Wf, bfv, Wo, bo, Wp, bp,
                                (float*)d_out, mol, stats, bar);
}